// Round 1
// baseline (1083.231 us; speedup 1.0000x reference)
//
#include <hip/hip_runtime.h>

// Problem constants
#define B_TOK 4096
#define HDIM 1024
#define IDIM 4096
#define NEXP 8
#define NSLOT 8192          // B_TOK * TOP_K
#define MAX_TILES 72        // ceil-sum bound: 64 + 7 = 71, +1 spare

using short8   = __attribute__((ext_vector_type(8))) short;
using bf16x8   = __attribute__((ext_vector_type(8))) __bf16;
using f32x4    = __attribute__((ext_vector_type(4))) float;
using int4v    = __attribute__((ext_vector_type(4))) int;
using uint2v   = __attribute__((ext_vector_type(2))) unsigned int;
using ushort4v = __attribute__((ext_vector_type(4))) unsigned short;
using float4v  = __attribute__((ext_vector_type(4))) float;

// meta layout (ints)
#define MC_COUNT   0
#define MC_CURSOR  8
#define MC_OFFS    16
#define MC_NTILES  25
#define MC_TILE_E  32
#define MC_TILE_M0 104
#define MC_TILE_RW 176
#define META_INTS  256

__device__ __forceinline__ unsigned short f2bf(float f) {
  unsigned u = __float_as_uint(f);
  u += 0x7FFFu + ((u >> 16) & 1u);   // RNE
  return (unsigned short)(u >> 16);
}
__device__ __forceinline__ float bf2f(unsigned short h) {
  return __uint_as_float(((unsigned)h) << 16);
}
__device__ __forceinline__ f32x4 mfma_bf16(short8 a, short8 b, f32x4 c) {
  return __builtin_amdgcn_mfma_f32_16x16x32_bf16(
      __builtin_bit_cast(bf16x8, a), __builtin_bit_cast(bf16x8, b), c, 0, 0, 0);
}

__global__ void init_kernel(int* meta) {
  if (threadIdx.x < 32) meta[threadIdx.x] = 0;
}

// One wave per token: logits = x@Wr + br + noise; top-2; softmax-of-2.
__global__ __launch_bounds__(256) void router_kernel(
    const float* __restrict__ x, const float* __restrict__ noise,
    const float* __restrict__ Wr, const float* __restrict__ br,
    int* __restrict__ meta, int* __restrict__ idxmap, float* __restrict__ wmap) {
  int tok = blockIdx.x * 4 + (threadIdx.x >> 6);
  int l = threadIdx.x & 63;
  const float* xr = x + (size_t)tok * HDIM;
  float acc[8];
#pragma unroll
  for (int e = 0; e < 8; e++) acc[e] = 0.f;
  for (int h = l; h < HDIM; h += 64) {
    float xv = xr[h];
    float4v w0 = *(const float4v*)(Wr + (size_t)h * 8);
    float4v w1 = *(const float4v*)(Wr + (size_t)h * 8 + 4);
    acc[0] += xv * w0[0]; acc[1] += xv * w0[1];
    acc[2] += xv * w0[2]; acc[3] += xv * w0[3];
    acc[4] += xv * w1[0]; acc[5] += xv * w1[1];
    acc[6] += xv * w1[2]; acc[7] += xv * w1[3];
  }
#pragma unroll
  for (int off = 32; off > 0; off >>= 1) {
#pragma unroll
    for (int e = 0; e < 8; e++) acc[e] += __shfl_xor(acc[e], off, 64);
  }
  if (l == 0) {
    float y[8];
#pragma unroll
    for (int e = 0; e < 8; e++) y[e] = acc[e] + br[e] + noise[(size_t)tok * 8 + e];
    int e0 = 0;
#pragma unroll
    for (int e = 1; e < 8; e++) if (y[e] > y[e0]) e0 = e;   // ties -> lower idx
    int e1 = (e0 == 0) ? 1 : 0;
#pragma unroll
    for (int e = 0; e < 8; e++) if (e != e0 && y[e] > y[e1]) e1 = e;
    float w0 = 1.f / (1.f + __expf(y[e1] - y[e0]));          // softmax of 2
    idxmap[tok * 2] = e0; idxmap[tok * 2 + 1] = e1;
    wmap[tok * 2] = w0;   wmap[tok * 2 + 1] = 1.f - w0;
    atomicAdd(&meta[MC_COUNT + e0], 1);
    atomicAdd(&meta[MC_COUNT + e1], 1);
  }
}

__global__ void scan_kernel(int* meta) {
  int off = 0;
  for (int e = 0; e < 8; e++) { meta[MC_OFFS + e] = off; off += meta[MC_COUNT + e]; }
  meta[MC_OFFS + 8] = off;
  int t = 0;
  for (int e = 0; e < 8; e++) {
    int n = meta[MC_COUNT + e], o = meta[MC_OFFS + e];
    for (int i = 0; i < n; i += 128) {
      meta[MC_TILE_E + t] = e;
      meta[MC_TILE_M0 + t] = o + i;
      meta[MC_TILE_RW + t] = (n - i < 128) ? (n - i) : 128;
      t++;
    }
  }
  meta[MC_NTILES] = t;
}

// Slot assignment + gather x rows (fp32 -> bf16) into slot order.
__global__ __launch_bounds__(256) void place_kernel(
    const float* __restrict__ x, int* __restrict__ meta,
    const int* __restrict__ idxmap, int* __restrict__ slotmap,
    unsigned short* __restrict__ x_g) {
  int b = blockIdx.x;
  __shared__ int ss[2];
  if (threadIdx.x == 0) {
    int e0 = idxmap[b * 2], e1 = idxmap[b * 2 + 1];
    int s0 = meta[MC_OFFS + e0] + atomicAdd(&meta[MC_CURSOR + e0], 1);
    int s1 = meta[MC_OFFS + e1] + atomicAdd(&meta[MC_CURSOR + e1], 1);
    ss[0] = s0; ss[1] = s1;
    slotmap[b * 2] = s0; slotmap[b * 2 + 1] = s1;
  }
  __syncthreads();
  int s0 = ss[0], s1 = ss[1];
  int h = threadIdx.x * 4;
  float4v v = *(const float4v*)(x + (size_t)b * HDIM + h);
  uint2v p;
  p[0] = (unsigned)f2bf(v[0]) | ((unsigned)f2bf(v[1]) << 16);
  p[1] = (unsigned)f2bf(v[2]) | ((unsigned)f2bf(v[3]) << 16);
  *(uint2v*)(x_g + (size_t)s0 * HDIM + h) = p;
  *(uint2v*)(x_g + (size_t)s1 * HDIM + h) = p;
}

// Grouped GEMM1 + fused bias + SwiGLU. Tile 128m x (64+64)n-interleaved, BK=64.
// Bs rows n<64 -> W_in col j0+n (x1 half); n>=64 -> col 4096+j0+(n-64) (x2 half).
// Wave layout: 4 waves stacked on M (32 rows each), full 128 acc cols per wave,
// so SwiGLU pair (nf, nf+4) is lane-aligned.
__global__ __launch_bounds__(256) void gemm1_kernel(
    const unsigned short* __restrict__ x_g, const float* __restrict__ W_in,
    const float* __restrict__ b_in, unsigned short* __restrict__ a_buf,
    const int* __restrict__ meta) {
  int t = blockIdx.x;
  if (t >= meta[MC_NTILES]) return;
  int e = meta[MC_TILE_E + t];
  int m0 = meta[MC_TILE_M0 + t];
  int rows = meta[MC_TILE_RW + t];
  int j0 = blockIdx.y * 64;
  const float* Bp = W_in + (size_t)e * (1024u * 8192u);

  // stride 72 bf16 (144B = 36 words == 4 mod 32): balanced banks for b128 ops
  __shared__ __align__(16) unsigned short As[128 * 72];
  __shared__ __align__(16) unsigned short Bs[128 * 72];

  int tid = threadIdx.x;
  int l = tid & 63, w = tid >> 6, g = l >> 4, ln = l & 15;

  f32x4 acc[2][8];
#pragma unroll
  for (int mf = 0; mf < 2; mf++)
#pragma unroll
    for (int nf = 0; nf < 8; nf++) acc[mf][nf] = (f32x4){0.f, 0.f, 0.f, 0.f};

  for (int kt = 0; kt < 16; kt++) {
    // stage A: 128 rows x 64 k bf16, 16B chunks
#pragma unroll
    for (int i = 0; i < 4; i++) {
      int q = tid + i * 256;
      int r = q >> 3, c = q & 7;
      int rr = r < rows ? r : rows - 1;  // clamp: dup row, masked at store
      int4v v = *(const int4v*)(x_g + (size_t)(m0 + rr) * HDIM + kt * 64 + c * 8);
      *(int4v*)(&As[r * 72 + c * 8]) = v;
    }
    // stage B: fp32 strided loads (coalesced across n), convert, b128 write
#pragma unroll
    for (int i = 0; i < 4; i++) {
      int q = tid + i * 256;
      int kc = q >> 7, n = q & 127;
      int col = (n < 64) ? (j0 + n) : (4096 + j0 + n - 64);
      const float* src = Bp + (size_t)(kt * 64 + kc * 8) * 8192 + col;
      unsigned short u[8];
#pragma unroll
      for (int j = 0; j < 8; j++) u[j] = f2bf(src[(size_t)j * 8192]);
      int4v p;
      p[0] = (int)((unsigned)u[0] | ((unsigned)u[1] << 16));
      p[1] = (int)((unsigned)u[2] | ((unsigned)u[3] << 16));
      p[2] = (int)((unsigned)u[4] | ((unsigned)u[5] << 16));
      p[3] = (int)((unsigned)u[6] | ((unsigned)u[7] << 16));
      *(int4v*)(&Bs[n * 72 + kc * 8]) = p;
    }
    __syncthreads();
#pragma unroll
    for (int ks = 0; ks < 2; ks++) {
      short8 a0 = *(const short8*)(&As[(w * 32 + ln) * 72 + ks * 32 + g * 8]);
      short8 a1 = *(const short8*)(&As[(w * 32 + 16 + ln) * 72 + ks * 32 + g * 8]);
#pragma unroll
      for (int nf = 0; nf < 8; nf++) {
        short8 bv = *(const short8*)(&Bs[(nf * 16 + ln) * 72 + ks * 32 + g * 8]);
        acc[0][nf] = mfma_bf16(a0, bv, acc[0][nf]);
        acc[1][nf] = mfma_bf16(a1, bv, acc[1][nf]);
      }
    }
    __syncthreads();
  }
  // epilogue: h1 = C1 + b_in1, h2 = C2 + b_in2, a = h1 * sigmoid(h2)
#pragma unroll
  for (int mf = 0; mf < 2; mf++) {
#pragma unroll
    for (int nf = 0; nf < 4; nf++) {
      int jl = nf * 16 + ln;
      float b1 = b_in[(size_t)e * 8192 + j0 + jl];
      float b2 = b_in[(size_t)e * 8192 + 4096 + j0 + jl];
#pragma unroll
      for (int r = 0; r < 4; r++) {
        int m = w * 32 + mf * 16 + g * 4 + r;
        if (m < rows) {
          float h1 = acc[mf][nf][r] + b1;
          float h2 = acc[mf][nf + 4][r] + b2;
          float v = h1 / (1.f + __expf(-h2));
          a_buf[(size_t)(m0 + m) * IDIM + j0 + jl] = f2bf(v);
        }
      }
    }
  }
}

// Grouped GEMM2: buf2 = a @ W_out[e] + b_out[e]. Tile 128x128, K=4096.
__global__ __launch_bounds__(256) void gemm2_kernel(
    const unsigned short* __restrict__ a_buf, const float* __restrict__ W_out,
    const float* __restrict__ b_out, unsigned short* __restrict__ buf2,
    const int* __restrict__ meta) {
  int t = blockIdx.x;
  if (t >= meta[MC_NTILES]) return;
  int e = meta[MC_TILE_E + t];
  int m0 = meta[MC_TILE_M0 + t];
  int rows = meta[MC_TILE_RW + t];
  int n0 = blockIdx.y * 128;
  const float* Bp = W_out + (size_t)e * (4096u * 1024u);

  __shared__ __align__(16) unsigned short As[128 * 72];
  __shared__ __align__(16) unsigned short Bs[128 * 72];

  int tid = threadIdx.x;
  int l = tid & 63, w = tid >> 6, g = l >> 4, ln = l & 15;

  f32x4 acc[2][8];
#pragma unroll
  for (int mf = 0; mf < 2; mf++)
#pragma unroll
    for (int nf = 0; nf < 8; nf++) acc[mf][nf] = (f32x4){0.f, 0.f, 0.f, 0.f};

  for (int kt = 0; kt < 64; kt++) {
#pragma unroll
    for (int i = 0; i < 4; i++) {
      int q = tid + i * 256;
      int r = q >> 3, c = q & 7;
      int rr = r < rows ? r : rows - 1;
      int4v v = *(const int4v*)(a_buf + (size_t)(m0 + rr) * IDIM + kt * 64 + c * 8);
      *(int4v*)(&As[r * 72 + c * 8]) = v;
    }
#pragma unroll
    for (int i = 0; i < 4; i++) {
      int q = tid + i * 256;
      int kc = q >> 7, n = q & 127;
      const float* src = Bp + (size_t)(kt * 64 + kc * 8) * 1024 + n0 + n;
      unsigned short u[8];
#pragma unroll
      for (int j = 0; j < 8; j++) u[j] = f2bf(src[(size_t)j * 1024]);
      int4v p;
      p[0] = (int)((unsigned)u[0] | ((unsigned)u[1] << 16));
      p[1] = (int)((unsigned)u[2] | ((unsigned)u[3] << 16));
      p[2] = (int)((unsigned)u[4] | ((unsigned)u[5] << 16));
      p[3] = (int)((unsigned)u[6] | ((unsigned)u[7] << 16));
      *(int4v*)(&Bs[n * 72 + kc * 8]) = p;
    }
    __syncthreads();
#pragma unroll
    for (int ks = 0; ks < 2; ks++) {
      short8 a0 = *(const short8*)(&As[(w * 32 + ln) * 72 + ks * 32 + g * 8]);
      short8 a1 = *(const short8*)(&As[(w * 32 + 16 + ln) * 72 + ks * 32 + g * 8]);
#pragma unroll
      for (int nf = 0; nf < 8; nf++) {
        short8 bv = *(const short8*)(&Bs[(nf * 16 + ln) * 72 + ks * 32 + g * 8]);
        acc[0][nf] = mfma_bf16(a0, bv, acc[0][nf]);
        acc[1][nf] = mfma_bf16(a1, bv, acc[1][nf]);
      }
    }
    __syncthreads();
  }
#pragma unroll
  for (int mf = 0; mf < 2; mf++) {
#pragma unroll
    for (int nf = 0; nf < 8; nf++) {
      int nl = nf * 16 + ln;
      float bo = b_out[(size_t)e * 1024 + n0 + nl];
#pragma unroll
      for (int r = 0; r < 4; r++) {
        int m = w * 32 + mf * 16 + g * 4 + r;
        if (m < rows) {
          buf2[(size_t)(m0 + m) * HDIM + n0 + nl] = f2bf(acc[mf][nf][r] + bo);
        }
      }
    }
  }
}

// out[b] = w0 * buf2[slot0] + w1 * buf2[slot1]  (fp32, deterministic order)
__global__ __launch_bounds__(256) void combine_kernel(
    const unsigned short* __restrict__ buf2, const int* __restrict__ slotmap,
    const float* __restrict__ wmap, float* __restrict__ out) {
  int i = blockIdx.x * 256 + threadIdx.x;
  int base = i * 4;
  int b = base >> 10, h = base & 1023;
  int s0 = slotmap[b * 2], s1 = slotmap[b * 2 + 1];
  float w0 = wmap[b * 2], w1 = wmap[b * 2 + 1];
  ushort4v c0 = *(const ushort4v*)(buf2 + (size_t)s0 * HDIM + h);
  ushort4v c1 = *(const ushort4v*)(buf2 + (size_t)s1 * HDIM + h);
  float4v o;
#pragma unroll
  for (int j = 0; j < 4; j++) o[j] = w0 * bf2f(c0[j]) + w1 * bf2f(c1[j]);
  *(float4v*)(out + base) = o;
}

extern "C" void kernel_launch(void* const* d_in, const int* in_sizes, int n_in,
                              void* d_out, int out_size, void* d_ws, size_t ws_size,
                              hipStream_t stream) {
  const float* x     = (const float*)d_in[0];
  const float* noise = (const float*)d_in[1];
  const float* Wr    = (const float*)d_in[2];
  const float* br    = (const float*)d_in[3];
  const float* W_in  = (const float*)d_in[4];
  const float* b_in  = (const float*)d_in[5];
  const float* W_out = (const float*)d_in[6];
  const float* b_out = (const float*)d_in[7];
  float* out = (float*)d_out;

  // workspace layout (~100.8 MB)
  char* ws = (char*)d_ws;
  unsigned short* x_g   = (unsigned short*)ws;                          // 16 MB
  unsigned short* a_buf = (unsigned short*)(ws + (size_t)16777216);     // 64 MB
  unsigned short* buf2  = (unsigned short*)(ws + (size_t)83886080);     // 16 MB
  int* meta    = (int*)(ws + (size_t)100663296);
  int* idxmap  = meta + META_INTS;          // [4096][2]
  int* slotmap = idxmap + NSLOT;            // [4096][2]
  float* wmap  = (float*)(slotmap + NSLOT); // [4096][2]

  hipLaunchKernelGGL(init_kernel, dim3(1), dim3(64), 0, stream, meta);
  hipLaunchKernelGGL(router_kernel, dim3(B_TOK / 4), dim3(256), 0, stream,
                     x, noise, Wr, br, meta, idxmap, wmap);
  hipLaunchKernelGGL(scan_kernel, dim3(1), dim3(1), 0, stream, meta);
  hipLaunchKernelGGL(place_kernel, dim3(B_TOK), dim3(256), 0, stream,
                     x, meta, idxmap, slotmap, x_g);
  hipLaunchKernelGGL(gemm1_kernel, dim3(MAX_TILES, 64), dim3(256), 0, stream,
                     x_g, W_in, b_in, a_buf, meta);
  hipLaunchKernelGGL(gemm2_kernel, dim3(MAX_TILES, 8), dim3(256), 0, stream,
                     a_buf, W_out, b_out, buf2, meta);
  hipLaunchKernelGGL(combine_kernel, dim3((B_TOK * HDIM / 4) / 256), dim3(256), 0, stream,
                     buf2, slotmap, wmap, out);
}

// Round 2
// 892.255 us; speedup vs baseline: 1.2140x; 1.2140x over previous
//
#include <hip/hip_runtime.h>

// Problem constants
#define B_TOK 4096
#define HDIM 1024
#define IDIM 4096
#define NSLOT 8192          // B_TOK * TOP_K
#define MAX_TILES 72        // ceil-sum bound: 64 + 7 = 71, +1 spare

using short8   = __attribute__((ext_vector_type(8))) short;
using bf16x8   = __attribute__((ext_vector_type(8))) __bf16;
using f32x4    = __attribute__((ext_vector_type(4))) float;
using int4v    = __attribute__((ext_vector_type(4))) int;
using uint2v   = __attribute__((ext_vector_type(2))) unsigned int;
using ushort4v = __attribute__((ext_vector_type(4))) unsigned short;
using float4v  = __attribute__((ext_vector_type(4))) float;

// meta layout (ints)
#define MC_COUNT   0
#define MC_CURSOR  8
#define MC_OFFS    16
#define MC_NTILES  25
#define MC_TILE_E  32
#define MC_TILE_M0 104
#define MC_TILE_RW 176
#define META_INTS  256

__device__ __forceinline__ unsigned short f2bf(float f) {
  unsigned u = __float_as_uint(f);
  u += 0x7FFFu + ((u >> 16) & 1u);   // RNE
  return (unsigned short)(u >> 16);
}
__device__ __forceinline__ float bf2f(unsigned short h) {
  return __uint_as_float(((unsigned)h) << 16);
}
__device__ __forceinline__ f32x4 mfma_bf16(short8 a, short8 b, f32x4 c) {
  return __builtin_amdgcn_mfma_f32_16x16x32_bf16(
      __builtin_bit_cast(bf16x8, a), __builtin_bit_cast(bf16x8, b), c, 0, 0, 0);
}
// async global->LDS, 16B per lane; LDS dest = wave-uniform base + lane*16
__device__ __forceinline__ void gload16(const unsigned short* g, unsigned short* l) {
  __builtin_amdgcn_global_load_lds(
      (const __attribute__((address_space(1))) unsigned int*)g,
      (__attribute__((address_space(3))) unsigned int*)l, 16, 0, 0);
}

__global__ void init_kernel(int* meta) {
  if (threadIdx.x < 32) meta[threadIdx.x] = 0;
}

// One wave per token: logits = x@Wr + br + noise; top-2; softmax-of-2.
__global__ __launch_bounds__(256) void router_kernel(
    const float* __restrict__ x, const float* __restrict__ noise,
    const float* __restrict__ Wr, const float* __restrict__ br,
    int* __restrict__ meta, int* __restrict__ idxmap, float* __restrict__ wmap) {
  int tok = blockIdx.x * 4 + (threadIdx.x >> 6);
  int l = threadIdx.x & 63;
  const float* xr = x + (size_t)tok * HDIM;
  float acc[8];
#pragma unroll
  for (int e = 0; e < 8; e++) acc[e] = 0.f;
  for (int h = l; h < HDIM; h += 64) {
    float xv = xr[h];
    float4v w0 = *(const float4v*)(Wr + (size_t)h * 8);
    float4v w1 = *(const float4v*)(Wr + (size_t)h * 8 + 4);
    acc[0] += xv * w0[0]; acc[1] += xv * w0[1];
    acc[2] += xv * w0[2]; acc[3] += xv * w0[3];
    acc[4] += xv * w1[0]; acc[5] += xv * w1[1];
    acc[6] += xv * w1[2]; acc[7] += xv * w1[3];
  }
#pragma unroll
  for (int off = 32; off > 0; off >>= 1) {
#pragma unroll
    for (int e = 0; e < 8; e++) acc[e] += __shfl_xor(acc[e], off, 64);
  }
  if (l == 0) {
    float y[8];
#pragma unroll
    for (int e = 0; e < 8; e++) y[e] = acc[e] + br[e] + noise[(size_t)tok * 8 + e];
    int e0 = 0;
#pragma unroll
    for (int e = 1; e < 8; e++) if (y[e] > y[e0]) e0 = e;   // ties -> lower idx
    int e1 = (e0 == 0) ? 1 : 0;
#pragma unroll
    for (int e = 0; e < 8; e++) if (e != e0 && y[e] > y[e1]) e1 = e;
    float w0 = 1.f / (1.f + __expf(y[e1] - y[e0]));          // softmax of 2
    idxmap[tok * 2] = e0; idxmap[tok * 2 + 1] = e1;
    wmap[tok * 2] = w0;   wmap[tok * 2 + 1] = 1.f - w0;
    atomicAdd(&meta[MC_COUNT + e0], 1);
    atomicAdd(&meta[MC_COUNT + e1], 1);
  }
}

__global__ void scan_kernel(int* meta) {
  int off = 0;
  for (int e = 0; e < 8; e++) { meta[MC_OFFS + e] = off; off += meta[MC_COUNT + e]; }
  meta[MC_OFFS + 8] = off;
  int t = 0;
  for (int e = 0; e < 8; e++) {
    int n = meta[MC_COUNT + e], o = meta[MC_OFFS + e];
    for (int i = 0; i < n; i += 128) {
      meta[MC_TILE_E + t] = e;
      meta[MC_TILE_M0 + t] = o + i;
      meta[MC_TILE_RW + t] = (n - i < 128) ? (n - i) : 128;
      t++;
    }
  }
  meta[MC_NTILES] = t;
}

// Slot assignment + gather x rows (fp32 -> bf16) into slot order.
__global__ __launch_bounds__(256) void place_kernel(
    const float* __restrict__ x, int* __restrict__ meta,
    const int* __restrict__ idxmap, int* __restrict__ slotmap,
    unsigned short* __restrict__ x_g) {
  int b = blockIdx.x;
  __shared__ int ss[2];
  if (threadIdx.x == 0) {
    int e0 = idxmap[b * 2], e1 = idxmap[b * 2 + 1];
    int s0 = meta[MC_OFFS + e0] + atomicAdd(&meta[MC_CURSOR + e0], 1);
    int s1 = meta[MC_OFFS + e1] + atomicAdd(&meta[MC_CURSOR + e1], 1);
    ss[0] = s0; ss[1] = s1;
    slotmap[b * 2] = s0; slotmap[b * 2 + 1] = s1;
  }
  __syncthreads();
  int s0 = ss[0], s1 = ss[1];
  int h = threadIdx.x * 4;
  float4v v = *(const float4v*)(x + (size_t)b * HDIM + h);
  uint2v p;
  p[0] = (unsigned)f2bf(v[0]) | ((unsigned)f2bf(v[1]) << 16);
  p[1] = (unsigned)f2bf(v[2]) | ((unsigned)f2bf(v[3]) << 16);
  *(uint2v*)(x_g + (size_t)s0 * HDIM + h) = p;
  *(uint2v*)(x_g + (size_t)s1 * HDIM + h) = p;
}

// ---- Path A: weight transpose-convert preps ----
// W_in fp32 [8][1024][8192] -> W_in_t bf16 [e][J(64)][128 rows][1024 k]
// panel rows 0..63 = x1 cols J*64.., rows 64..127 = x2 cols 4096+J*64..
__global__ __launch_bounds__(256) void prep_win_kernel(
    const float* __restrict__ W_in, unsigned short* __restrict__ Wt) {
  int e = blockIdx.z, k0 = blockIdx.y * 64, n0 = blockIdx.x * 64;
  __shared__ unsigned short T[64 * 72];
  int tid = threadIdx.x;
#pragma unroll
  for (int i = 0; i < 4; i++) {
    int q = i * 256 + tid;
    int kr = q >> 4, nc = (q & 15) * 4;
    float4v v = *(const float4v*)(W_in + ((size_t)e * 1024 + k0 + kr) * 8192 + n0 + nc);
#pragma unroll
    for (int j = 0; j < 4; j++) T[(nc + j) * 72 + kr] = f2bf(v[j]);
  }
  __syncthreads();
  int J = (n0 & 4095) >> 6;
  int rwb = (n0 >= 4096) ? 64 : 0;
  unsigned short* ob = Wt + (((size_t)e * 64 + J) * 128 + rwb) * 1024;
#pragma unroll
  for (int i = 0; i < 4; i++) {
    int q = i * 256 + tid;
    int nr = q >> 4, kc = (q & 15) * 4;
    ushort4v u;
#pragma unroll
    for (int j = 0; j < 4; j++) u[j] = T[nr * 72 + kc + j];
    *(ushort4v*)(ob + (size_t)nr * 1024 + k0 + kc) = u;
  }
}

// W_out fp32 [8][4096][1024] -> W_out_t bf16 [e][n=1024][k=4096]
__global__ __launch_bounds__(256) void prep_wout_kernel(
    const float* __restrict__ W_out, unsigned short* __restrict__ Wt) {
  int e = blockIdx.z, k0 = blockIdx.y * 64, n0 = blockIdx.x * 64;
  __shared__ unsigned short T[64 * 72];
  int tid = threadIdx.x;
#pragma unroll
  for (int i = 0; i < 4; i++) {
    int q = i * 256 + tid;
    int kr = q >> 4, nc = (q & 15) * 4;
    float4v v = *(const float4v*)(W_out + ((size_t)e * 4096 + k0 + kr) * 1024 + n0 + nc);
#pragma unroll
    for (int j = 0; j < 4; j++) T[(nc + j) * 72 + kr] = f2bf(v[j]);
  }
  __syncthreads();
  unsigned short* ob = Wt + ((size_t)e * 1024 + n0) * 4096;
#pragma unroll
  for (int i = 0; i < 4; i++) {
    int q = i * 256 + tid;
    int nr = q >> 4, kc = (q & 15) * 4;
    ushort4v u;
#pragma unroll
    for (int j = 0; j < 4; j++) u[j] = T[nr * 72 + kc + j];
    *(ushort4v*)(ob + (size_t)nr * 4096 + k0 + kc) = u;
  }
}

// ---- Path A GEMM1: m97-style, global_load_lds + XOR-swizzled frag reads ----
// LDS linear [128][64] bf16; source column-unit pre-swizzled so LDS holds
// LDS[row][u] = A[row][u ^ (row&7)] (16B units); reads apply same XOR.
__global__ __launch_bounds__(256) void gemm1a_kernel(
    const unsigned short* __restrict__ x_g, const unsigned short* __restrict__ Wt,
    const float* __restrict__ b_in, unsigned short* __restrict__ a_buf,
    const int* __restrict__ meta) {
  int t = blockIdx.x;
  if (t >= meta[MC_NTILES]) return;
  int e = meta[MC_TILE_E + t];
  int m0 = meta[MC_TILE_M0 + t];
  int rows = meta[MC_TILE_RW + t];
  int J = blockIdx.y;
  const unsigned short* Wp = Wt + (((size_t)e * 64 + J) << 17);  // *128*1024

  __shared__ __align__(16) unsigned short As[128 * 64];
  __shared__ __align__(16) unsigned short Bs[128 * 64];

  int tid = threadIdx.x, l = tid & 63, w = tid >> 6, g = l >> 4, ln = l & 15;
  int lr = l >> 3;
  int uc = (l & 7) ^ lr;   // swizzled source 16B-unit (row&7 == lr here)

  const unsigned short* sA[4]; const unsigned short* sB[4];
  unsigned short* dA[4]; unsigned short* dB[4];
#pragma unroll
  for (int i = 0; i < 4; i++) {
    int c = w * 4 + i;          // 1KB chunk 0..15
    int r = c * 8 + lr;         // tile row 0..127
    int ra = r < rows ? r : rows - 1;
    sA[i] = x_g + (size_t)(m0 + ra) * HDIM + uc * 8;
    sB[i] = Wp + (size_t)r * 1024 + uc * 8;
    dA[i] = &As[c * 512 + l * 8];
    dB[i] = &Bs[c * 512 + l * 8];
  }

  f32x4 acc[2][8];
#pragma unroll
  for (int mf = 0; mf < 2; mf++)
#pragma unroll
    for (int nf = 0; nf < 8; nf++) acc[mf][nf] = (f32x4){0.f, 0.f, 0.f, 0.f};

  for (int kt = 0; kt < 16; kt++) {
#pragma unroll
    for (int i = 0; i < 4; i++) gload16(sA[i] + kt * 64, dA[i]);
#pragma unroll
    for (int i = 0; i < 4; i++) gload16(sB[i] + kt * 64, dB[i]);
    __syncthreads();
#pragma unroll
    for (int ks = 0; ks < 2; ks++) {
      int u0 = (((ks * 4 + g) ^ (ln & 7)) << 3);
      int r0 = w * 32 + ln;
      short8 a0 = *(const short8*)&As[r0 * 64 + u0];
      short8 a1 = *(const short8*)&As[(r0 + 16) * 64 + u0];
#pragma unroll
      for (int nf = 0; nf < 8; nf++) {
        short8 bv = *(const short8*)&Bs[(nf * 16 + ln) * 64 + u0];
        acc[0][nf] = mfma_bf16(a0, bv, acc[0][nf]);
        acc[1][nf] = mfma_bf16(a1, bv, acc[1][nf]);
      }
    }
    __syncthreads();
  }
  // fused bias + SwiGLU epilogue; acc col nf<4 = x1, nf+4 = x2 (same j)
#pragma unroll
  for (int mf = 0; mf < 2; mf++) {
#pragma unroll
    for (int nf = 0; nf < 4; nf++) {
      int jl = nf * 16 + ln;
      float b1 = b_in[(size_t)e * 8192 + J * 64 + jl];
      float b2 = b_in[(size_t)e * 8192 + 4096 + J * 64 + jl];
#pragma unroll
      for (int r = 0; r < 4; r++) {
        int m = w * 32 + mf * 16 + g * 4 + r;
        if (m < rows) {
          float h1 = acc[mf][nf][r] + b1;
          float h2 = acc[mf][nf + 4][r] + b2;
          a_buf[(size_t)(m0 + m) * IDIM + J * 64 + jl] = f2bf(h1 / (1.f + __expf(-h2)));
        }
      }
    }
  }
}

// ---- Path A GEMM2: 128m x 64n tile, K=4096, same staging/swizzle ----
__global__ __launch_bounds__(256) void gemm2a_kernel(
    const unsigned short* __restrict__ a_buf, const unsigned short* __restrict__ Wt,
    const float* __restrict__ b_out, unsigned short* __restrict__ buf2,
    const int* __restrict__ meta) {
  int t = blockIdx.x;
  if (t >= meta[MC_NTILES]) return;
  int e = meta[MC_TILE_E + t];
  int m0 = meta[MC_TILE_M0 + t];
  int rows = meta[MC_TILE_RW + t];
  int n0 = blockIdx.y * 64;
  const unsigned short* Wp = Wt + ((size_t)e * 1024 + n0) * 4096;  // 64 rows x 4096

  __shared__ __align__(16) unsigned short As[128 * 64];
  __shared__ __align__(16) unsigned short Bs[64 * 64];

  int tid = threadIdx.x, l = tid & 63, w = tid >> 6, g = l >> 4, ln = l & 15;
  int lr = l >> 3;
  int uc = (l & 7) ^ lr;

  const unsigned short* sA[4]; const unsigned short* sB[2];
  unsigned short* dA[4]; unsigned short* dB[2];
#pragma unroll
  for (int i = 0; i < 4; i++) {
    int c = w * 4 + i;
    int r = c * 8 + lr;
    int ra = r < rows ? r : rows - 1;
    sA[i] = a_buf + (size_t)(m0 + ra) * IDIM + uc * 8;
    dA[i] = &As[c * 512 + l * 8];
  }
#pragma unroll
  for (int i = 0; i < 2; i++) {
    int c = w * 2 + i;          // 8 chunks of Bs
    int r = c * 8 + lr;         // 0..63
    sB[i] = Wp + (size_t)r * 4096 + uc * 8;
    dB[i] = &Bs[c * 512 + l * 8];
  }

  f32x4 acc[2][4];
#pragma unroll
  for (int mf = 0; mf < 2; mf++)
#pragma unroll
    for (int nf = 0; nf < 4; nf++) acc[mf][nf] = (f32x4){0.f, 0.f, 0.f, 0.f};

  for (int kt = 0; kt < 64; kt++) {
#pragma unroll
    for (int i = 0; i < 4; i++) gload16(sA[i] + kt * 64, dA[i]);
#pragma unroll
    for (int i = 0; i < 2; i++) gload16(sB[i] + kt * 64, dB[i]);
    __syncthreads();
#pragma unroll
    for (int ks = 0; ks < 2; ks++) {
      int u0 = (((ks * 4 + g) ^ (ln & 7)) << 3);
      int r0 = w * 32 + ln;
      short8 a0 = *(const short8*)&As[r0 * 64 + u0];
      short8 a1 = *(const short8*)&As[(r0 + 16) * 64 + u0];
#pragma unroll
      for (int nf = 0; nf < 4; nf++) {
        short8 bv = *(const short8*)&Bs[(nf * 16 + ln) * 64 + u0];
        acc[0][nf] = mfma_bf16(a0, bv, acc[0][nf]);
        acc[1][nf] = mfma_bf16(a1, bv, acc[1][nf]);
      }
    }
    __syncthreads();
  }
#pragma unroll
  for (int mf = 0; mf < 2; mf++) {
#pragma unroll
    for (int nf = 0; nf < 4; nf++) {
      int nl = nf * 16 + ln;
      float bo = b_out[(size_t)e * 1024 + n0 + nl];
#pragma unroll
      for (int r = 0; r < 4; r++) {
        int m = w * 32 + mf * 16 + g * 4 + r;
        if (m < rows) {
          buf2[(size_t)(m0 + m) * HDIM + n0 + nl] = f2bf(acc[mf][nf][r] + bo);
        }
      }
    }
  }
}

// ---- Path B (fallback, small ws): round-1 gemms with in-kernel fp32 convert ----
__global__ __launch_bounds__(256) void gemm1_kernel(
    const unsigned short* __restrict__ x_g, const float* __restrict__ W_in,
    const float* __restrict__ b_in, unsigned short* __restrict__ a_buf,
    const int* __restrict__ meta) {
  int t = blockIdx.x;
  if (t >= meta[MC_NTILES]) return;
  int e = meta[MC_TILE_E + t];
  int m0 = meta[MC_TILE_M0 + t];
  int rows = meta[MC_TILE_RW + t];
  int j0 = blockIdx.y * 64;
  const float* Bp = W_in + (size_t)e * (1024u * 8192u);

  __shared__ __align__(16) unsigned short As[128 * 72];
  __shared__ __align__(16) unsigned short Bs[128 * 72];

  int tid = threadIdx.x;
  int l = tid & 63, w = tid >> 6, g = l >> 4, ln = l & 15;

  f32x4 acc[2][8];
#pragma unroll
  for (int mf = 0; mf < 2; mf++)
#pragma unroll
    for (int nf = 0; nf < 8; nf++) acc[mf][nf] = (f32x4){0.f, 0.f, 0.f, 0.f};

  for (int kt = 0; kt < 16; kt++) {
#pragma unroll
    for (int i = 0; i < 4; i++) {
      int q = tid + i * 256;
      int r = q >> 3, c = q & 7;
      int rr = r < rows ? r : rows - 1;
      int4v v = *(const int4v*)(x_g + (size_t)(m0 + rr) * HDIM + kt * 64 + c * 8);
      *(int4v*)(&As[r * 72 + c * 8]) = v;
    }
#pragma unroll
    for (int i = 0; i < 4; i++) {
      int q = tid + i * 256;
      int kc = q >> 7, n = q & 127;
      int col = (n < 64) ? (j0 + n) : (4096 + j0 + n - 64);
      const float* src = Bp + (size_t)(kt * 64 + kc * 8) * 8192 + col;
      unsigned short u[8];
#pragma unroll
      for (int j = 0; j < 8; j++) u[j] = f2bf(src[(size_t)j * 8192]);
      int4v p;
      p[0] = (int)((unsigned)u[0] | ((unsigned)u[1] << 16));
      p[1] = (int)((unsigned)u[2] | ((unsigned)u[3] << 16));
      p[2] = (int)((unsigned)u[4] | ((unsigned)u[5] << 16));
      p[3] = (int)((unsigned)u[6] | ((unsigned)u[7] << 16));
      *(int4v*)(&Bs[n * 72 + kc * 8]) = p;
    }
    __syncthreads();
#pragma unroll
    for (int ks = 0; ks < 2; ks++) {
      short8 a0 = *(const short8*)(&As[(w * 32 + ln) * 72 + ks * 32 + g * 8]);
      short8 a1 = *(const short8*)(&As[(w * 32 + 16 + ln) * 72 + ks * 32 + g * 8]);
#pragma unroll
      for (int nf = 0; nf < 8; nf++) {
        short8 bv = *(const short8*)(&Bs[(nf * 16 + ln) * 72 + ks * 32 + g * 8]);
        acc[0][nf] = mfma_bf16(a0, bv, acc[0][nf]);
        acc[1][nf] = mfma_bf16(a1, bv, acc[1][nf]);
      }
    }
    __syncthreads();
  }
#pragma unroll
  for (int mf = 0; mf < 2; mf++) {
#pragma unroll
    for (int nf = 0; nf < 4; nf++) {
      int jl = nf * 16 + ln;
      float b1 = b_in[(size_t)e * 8192 + j0 + jl];
      float b2 = b_in[(size_t)e * 8192 + 4096 + j0 + jl];
#pragma unroll
      for (int r = 0; r < 4; r++) {
        int m = w * 32 + mf * 16 + g * 4 + r;
        if (m < rows) {
          float h1 = acc[mf][nf][r] + b1;
          float h2 = acc[mf][nf + 4][r] + b2;
          float v = h1 / (1.f + __expf(-h2));
          a_buf[(size_t)(m0 + m) * IDIM + j0 + jl] = f2bf(v);
        }
      }
    }
  }
}

__global__ __launch_bounds__(256) void gemm2_kernel(
    const unsigned short* __restrict__ a_buf, const float* __restrict__ W_out,
    const float* __restrict__ b_out, unsigned short* __restrict__ buf2,
    const int* __restrict__ meta) {
  int t = blockIdx.x;
  if (t >= meta[MC_NTILES]) return;
  int e = meta[MC_TILE_E + t];
  int m0 = meta[MC_TILE_M0 + t];
  int rows = meta[MC_TILE_RW + t];
  int n0 = blockIdx.y * 128;
  const float* Bp = W_out + (size_t)e * (4096u * 1024u);

  __shared__ __align__(16) unsigned short As[128 * 72];
  __shared__ __align__(16) unsigned short Bs[128 * 72];

  int tid = threadIdx.x;
  int l = tid & 63, w = tid >> 6, g = l >> 4, ln = l & 15;

  f32x4 acc[2][8];
#pragma unroll
  for (int mf = 0; mf < 2; mf++)
#pragma unroll
    for (int nf = 0; nf < 8; nf++) acc[mf][nf] = (f32x4){0.f, 0.f, 0.f, 0.f};

  for (int kt = 0; kt < 64; kt++) {
#pragma unroll
    for (int i = 0; i < 4; i++) {
      int q = tid + i * 256;
      int r = q >> 3, c = q & 7;
      int rr = r < rows ? r : rows - 1;
      int4v v = *(const int4v*)(a_buf + (size_t)(m0 + rr) * IDIM + kt * 64 + c * 8);
      *(int4v*)(&As[r * 72 + c * 8]) = v;
    }
#pragma unroll
    for (int i = 0; i < 4; i++) {
      int q = tid + i * 256;
      int kc = q >> 7, n = q & 127;
      const float* src = Bp + (size_t)(kt * 64 + kc * 8) * 1024 + n0 + n;
      unsigned short u[8];
#pragma unroll
      for (int j = 0; j < 8; j++) u[j] = f2bf(src[(size_t)j * 1024]);
      int4v p;
      p[0] = (int)((unsigned)u[0] | ((unsigned)u[1] << 16));
      p[1] = (int)((unsigned)u[2] | ((unsigned)u[3] << 16));
      p[2] = (int)((unsigned)u[4] | ((unsigned)u[5] << 16));
      p[3] = (int)((unsigned)u[6] | ((unsigned)u[7] << 16));
      *(int4v*)(&Bs[n * 72 + kc * 8]) = p;
    }
    __syncthreads();
#pragma unroll
    for (int ks = 0; ks < 2; ks++) {
      short8 a0 = *(const short8*)(&As[(w * 32 + ln) * 72 + ks * 32 + g * 8]);
      short8 a1 = *(const short8*)(&As[(w * 32 + 16 + ln) * 72 + ks * 32 + g * 8]);
#pragma unroll
      for (int nf = 0; nf < 8; nf++) {
        short8 bv = *(const short8*)(&Bs[(nf * 16 + ln) * 72 + ks * 32 + g * 8]);
        acc[0][nf] = mfma_bf16(a0, bv, acc[0][nf]);
        acc[1][nf] = mfma_bf16(a1, bv, acc[1][nf]);
      }
    }
    __syncthreads();
  }
#pragma unroll
  for (int mf = 0; mf < 2; mf++) {
#pragma unroll
    for (int nf = 0; nf < 8; nf++) {
      int nl = nf * 16 + ln;
      float bo = b_out[(size_t)e * 1024 + n0 + nl];
#pragma unroll
      for (int r = 0; r < 4; r++) {
        int m = w * 32 + mf * 16 + g * 4 + r;
        if (m < rows) {
          buf2[(size_t)(m0 + m) * HDIM + n0 + nl] = f2bf(acc[mf][nf][r] + bo);
        }
      }
    }
  }
}

// out[b] = w0 * buf2[slot0] + w1 * buf2[slot1]  (fp32, deterministic order)
__global__ __launch_bounds__(256) void combine_kernel(
    const unsigned short* __restrict__ buf2, const int* __restrict__ slotmap,
    const float* __restrict__ wmap, float* __restrict__ out) {
  int i = blockIdx.x * 256 + threadIdx.x;
  int base = i * 4;
  int b = base >> 10, h = base & 1023;
  int s0 = slotmap[b * 2], s1 = slotmap[b * 2 + 1];
  float w0 = wmap[b * 2], w1 = wmap[b * 2 + 1];
  ushort4v c0 = *(const ushort4v*)(buf2 + (size_t)s0 * HDIM + h);
  ushort4v c1 = *(const ushort4v*)(buf2 + (size_t)s1 * HDIM + h);
  float4v o;
#pragma unroll
  for (int j = 0; j < 4; j++) o[j] = w0 * bf2f(c0[j]) + w1 * bf2f(c1[j]);
  *(float4v*)(out + base) = o;
}

extern "C" void kernel_launch(void* const* d_in, const int* in_sizes, int n_in,
                              void* d_out, int out_size, void* d_ws, size_t ws_size,
                              hipStream_t stream) {
  const float* x     = (const float*)d_in[0];
  const float* noise = (const float*)d_in[1];
  const float* Wr    = (const float*)d_in[2];
  const float* br    = (const float*)d_in[3];
  const float* W_in  = (const float*)d_in[4];
  const float* b_in  = (const float*)d_in[5];
  const float* W_out = (const float*)d_in[6];
  const float* b_out = (const float*)d_in[7];
  float* out = (float*)d_out;
  char* ws = (char*)d_ws;

  const size_t NEED_A = 218234880;  // 128M (Wt) + 16M (x_g/buf2) + 64M (a_buf) + maps
  if (ws_size >= NEED_A) {
    // Path A. Aliasing via stream order: W_out_t overwrites W_in_t after gemm1;
    // buf2 overwrites x_g after gemm1.
    unsigned short* W_in_t  = (unsigned short*)ws;                      // 128 MB
    unsigned short* W_out_t = W_in_t;                                   // 64 MB (after gemm1)
    unsigned short* x_g     = (unsigned short*)(ws + 134217728);        // 16 MB
    unsigned short* buf2    = x_g;                                      // (after gemm1)
    unsigned short* a_buf   = (unsigned short*)(ws + 150994944);        // 64 MB
    int* meta    = (int*)(ws + 218103808);
    int* idxmap  = meta + META_INTS;
    int* slotmap = idxmap + 2 * B_TOK;
    float* wmap  = (float*)(slotmap + 2 * B_TOK);

    hipLaunchKernelGGL(init_kernel, dim3(1), dim3(64), 0, stream, meta);
    hipLaunchKernelGGL(router_kernel, dim3(B_TOK / 4), dim3(256), 0, stream,
                       x, noise, Wr, br, meta, idxmap, wmap);
    hipLaunchKernelGGL(scan_kernel, dim3(1), dim3(1), 0, stream, meta);
    hipLaunchKernelGGL(place_kernel, dim3(B_TOK), dim3(256), 0, stream,
                       x, meta, idxmap, slotmap, x_g);
    hipLaunchKernelGGL(prep_win_kernel, dim3(128, 16, 8), dim3(256), 0, stream,
                       W_in, W_in_t);
    hipLaunchKernelGGL(gemm1a_kernel, dim3(MAX_TILES, 64), dim3(256), 0, stream,
                       x_g, W_in_t, b_in, a_buf, meta);
    hipLaunchKernelGGL(prep_wout_kernel, dim3(16, 64, 8), dim3(256), 0, stream,
                       W_out, W_out_t);
    hipLaunchKernelGGL(gemm2a_kernel, dim3(MAX_TILES, 16), dim3(256), 0, stream,
                       a_buf, W_out_t, b_out, buf2, meta);
    hipLaunchKernelGGL(combine_kernel, dim3((B_TOK * HDIM / 4) / 256), dim3(256), 0, stream,
                       buf2, slotmap, wmap, out);
  } else {
    // Path B (round-1 layout, ~101 MB)
    unsigned short* x_g   = (unsigned short*)ws;                        // 16 MB
    unsigned short* a_buf = (unsigned short*)(ws + (size_t)16777216);   // 64 MB
    unsigned short* buf2  = (unsigned short*)(ws + (size_t)83886080);   // 16 MB
    int* meta    = (int*)(ws + (size_t)100663296);
    int* idxmap  = meta + META_INTS;
    int* slotmap = idxmap + NSLOT;
    float* wmap  = (float*)(slotmap + NSLOT);

    hipLaunchKernelGGL(init_kernel, dim3(1), dim3(64), 0, stream, meta);
    hipLaunchKernelGGL(router_kernel, dim3(B_TOK / 4), dim3(256), 0, stream,
                       x, noise, Wr, br, meta, idxmap, wmap);
    hipLaunchKernelGGL(scan_kernel, dim3(1), dim3(1), 0, stream, meta);
    hipLaunchKernelGGL(place_kernel, dim3(B_TOK), dim3(256), 0, stream,
                       x, meta, idxmap, slotmap, x_g);
    hipLaunchKernelGGL(gemm1_kernel, dim3(MAX_TILES, 64), dim3(256), 0, stream,
                       x_g, W_in, b_in, a_buf, meta);
    hipLaunchKernelGGL(gemm2_kernel, dim3(MAX_TILES, 8), dim3(256), 0, stream,
                       a_buf, W_out, b_out, buf2, meta);
    hipLaunchKernelGGL(combine_kernel, dim3((B_TOK * HDIM / 4) / 256), dim3(256), 0, stream,
                       buf2, slotmap, wmap, out);
  }
}

// Round 3
// 504.001 us; speedup vs baseline: 2.1493x; 1.7703x over previous
//
#include <hip/hip_runtime.h>

// Problem constants
#define B_TOK 4096
#define HDIM 1024
#define IDIM 4096
#define NSLOT 8192          // B_TOK * TOP_K
#define MAX_TILES 72        // ceil-sum bound: 64 + 7 = 71, +1 spare

using short8   = __attribute__((ext_vector_type(8))) short;
using bf16x8   = __attribute__((ext_vector_type(8))) __bf16;
using f32x4    = __attribute__((ext_vector_type(4))) float;
using int4v    = __attribute__((ext_vector_type(4))) int;
using ushort4v = __attribute__((ext_vector_type(4))) unsigned short;
using float4v  = __attribute__((ext_vector_type(4))) float;

// meta layout (ints) — tile table only (ranks are atomic-free now)
#define MC_NTILES  25
#define MC_TILE_E  32
#define MC_TILE_M0 104
#define MC_TILE_RW 176
#define META_INTS  256

__device__ __forceinline__ unsigned short f2bf(float f) {
  unsigned u = __float_as_uint(f);
  u += 0x7FFFu + ((u >> 16) & 1u);   // RNE
  return (unsigned short)(u >> 16);
}
__device__ __forceinline__ float bf2f(unsigned short h) {
  return __uint_as_float(((unsigned)h) << 16);
}
__device__ __forceinline__ f32x4 mfma_bf16(short8 a, short8 b, f32x4 c) {
  return __builtin_amdgcn_mfma_f32_16x16x32_bf16(
      __builtin_bit_cast(bf16x8, a), __builtin_bit_cast(bf16x8, b), c, 0, 0, 0);
}
// async global->LDS, 16B per lane; LDS dest = wave-uniform base + lane*16
__device__ __forceinline__ void gload16(const unsigned short* g, unsigned short* l) {
  __builtin_amdgcn_global_load_lds(
      (const __attribute__((address_space(1))) unsigned int*)g,
      (__attribute__((address_space(3))) unsigned int*)l, 16, 0, 0);
}

// One wave per token: logits = x@Wr + br + noise; top-2; softmax-of-2.
// NO atomics (counts are recomputed deterministically in rank_kernel).
__global__ __launch_bounds__(256) void router_kernel(
    const float* __restrict__ x, const float* __restrict__ noise,
    const float* __restrict__ Wr, const float* __restrict__ br,
    int* __restrict__ idxmap, float* __restrict__ wmap) {
  int tok = blockIdx.x * 4 + (threadIdx.x >> 6);
  int l = threadIdx.x & 63;
  const float* xr = x + (size_t)tok * HDIM;
  float acc[8];
#pragma unroll
  for (int e = 0; e < 8; e++) acc[e] = 0.f;
  for (int h = l; h < HDIM; h += 64) {
    float xv = xr[h];
    float4v w0 = *(const float4v*)(Wr + (size_t)h * 8);
    float4v w1 = *(const float4v*)(Wr + (size_t)h * 8 + 4);
    acc[0] += xv * w0[0]; acc[1] += xv * w0[1];
    acc[2] += xv * w0[2]; acc[3] += xv * w0[3];
    acc[4] += xv * w1[0]; acc[5] += xv * w1[1];
    acc[6] += xv * w1[2]; acc[7] += xv * w1[3];
  }
#pragma unroll
  for (int off = 32; off > 0; off >>= 1) {
#pragma unroll
    for (int e = 0; e < 8; e++) acc[e] += __shfl_xor(acc[e], off, 64);
  }
  if (l == 0) {
    float y[8];
#pragma unroll
    for (int e = 0; e < 8; e++) y[e] = acc[e] + br[e] + noise[(size_t)tok * 8 + e];
    int e0 = 0;
#pragma unroll
    for (int e = 1; e < 8; e++) if (y[e] > y[e0]) e0 = e;   // ties -> lower idx
    int e1 = (e0 == 0) ? 1 : 0;
#pragma unroll
    for (int e = 0; e < 8; e++) if (e != e0 && y[e] > y[e1]) e1 = e;
    float w0 = 1.f / (1.f + __expf(y[e1] - y[e0]));          // softmax of 2
    idxmap[tok * 2] = e0; idxmap[tok * 2 + 1] = e1;
    wmap[tok * 2] = w0;   wmap[tok * 2 + 1] = 1.f - w0;
  }
}

// Deterministic slot ranks: one block, 1024 threads, 8 entries/thread.
// Packed per-expert counters: 8 experts x 16-bit fields across 4 words.
// slot[entry] = expert_base[e] + (# earlier entries with same e), entry order
// = (token, k). Also builds the tile table (replaces init+scan kernels).
__global__ __launch_bounds__(1024) void rank_kernel(
    const int* __restrict__ idxmap, int* __restrict__ slotmap,
    int* __restrict__ meta) {
  int tid = threadIdx.x, lane = tid & 63, wv = tid >> 6;
  __shared__ unsigned wtot[16][4];
  __shared__ unsigned woff[16][4];
  __shared__ unsigned offE[8];

  int es[8];
  unsigned p0 = 0, p1 = 0, p2 = 0, p3 = 0;
#pragma unroll
  for (int j = 0; j < 8; j++) {
    int e = idxmap[tid * 8 + j];
    es[j] = e;
    unsigned c = 1u << ((e & 1) * 16);
    if (e < 2) p0 += c; else if (e < 4) p1 += c;
    else if (e < 6) p2 += c; else p3 += c;
  }
  // wave-inclusive scan (4 packed words)
  unsigned i0 = p0, i1 = p1, i2 = p2, i3 = p3;
#pragma unroll
  for (int d = 1; d < 64; d <<= 1) {
    unsigned t0 = __shfl_up(i0, d, 64), t1 = __shfl_up(i1, d, 64);
    unsigned t2 = __shfl_up(i2, d, 64), t3 = __shfl_up(i3, d, 64);
    if (lane >= d) { i0 += t0; i1 += t1; i2 += t2; i3 += t3; }
  }
  if (lane == 63) { wtot[wv][0] = i0; wtot[wv][1] = i1; wtot[wv][2] = i2; wtot[wv][3] = i3; }
  __syncthreads();
  if (wv == 0 && lane < 16) {
    unsigned a0 = wtot[lane][0], a1 = wtot[lane][1], a2 = wtot[lane][2], a3 = wtot[lane][3];
    unsigned s0 = a0, s1 = a1, s2 = a2, s3 = a3;
#pragma unroll
    for (int d = 1; d < 16; d <<= 1) {
      unsigned t0 = __shfl_up(s0, d, 64), t1 = __shfl_up(s1, d, 64);
      unsigned t2 = __shfl_up(s2, d, 64), t3 = __shfl_up(s3, d, 64);
      if (lane >= d) { s0 += t0; s1 += t1; s2 += t2; s3 += t3; }
    }
    woff[lane][0] = s0 - a0; woff[lane][1] = s1 - a1;
    woff[lane][2] = s2 - a2; woff[lane][3] = s3 - a3;
    if (lane == 15) {
      unsigned t[8];
      t[0] = s0 & 0xFFFF; t[1] = s0 >> 16; t[2] = s1 & 0xFFFF; t[3] = s1 >> 16;
      t[4] = s2 & 0xFFFF; t[5] = s2 >> 16; t[6] = s3 & 0xFFFF; t[7] = s3 >> 16;
      unsigned off = 0; int tc = 0;
      for (int e = 0; e < 8; e++) {
        offE[e] = off;
        for (unsigned i = 0; i < t[e]; i += 128) {
          meta[MC_TILE_E + tc] = e;
          meta[MC_TILE_M0 + tc] = (int)(off + i);
          meta[MC_TILE_RW + tc] = (int)((t[e] - i < 128u) ? (t[e] - i) : 128u);
          tc++;
        }
        off += t[e];
      }
      meta[MC_NTILES] = tc;
    }
  }
  __syncthreads();
  // thread-exclusive base per field
  unsigned e0w = i0 - p0 + woff[wv][0];
  unsigned e1w = i1 - p1 + woff[wv][1];
  unsigned e2w = i2 - p2 + woff[wv][2];
  unsigned e3w = i3 - p3 + woff[wv][3];
#pragma unroll
  for (int j = 0; j < 8; j++) {
    int e = es[j];
    unsigned sh = (unsigned)(e & 1) * 16;
    unsigned c = 1u << sh, v;
    if (e < 2)      { v = (e0w >> sh) & 0xFFFF; e0w += c; }
    else if (e < 4) { v = (e1w >> sh) & 0xFFFF; e1w += c; }
    else if (e < 6) { v = (e2w >> sh) & 0xFFFF; e2w += c; }
    else            { v = (e3w >> sh) & 0xFFFF; e3w += c; }
    slotmap[tid * 8 + j] = (int)(offE[e] + v);
  }
}

// Pure scatter-gather: x row (fp32) -> bf16 to both slots. No atomics.
__global__ __launch_bounds__(256) void place_kernel(
    const float* __restrict__ x, const int* __restrict__ slotmap,
    unsigned short* __restrict__ x_g) {
  int tok = blockIdx.x * 2 + (threadIdx.x >> 7);
  int h = (threadIdx.x & 127) * 8;
  const float* xr = x + (size_t)tok * HDIM + h;
  float4v v0 = *(const float4v*)xr;
  float4v v1 = *(const float4v*)(xr + 4);
  int4v p;
  p[0] = (int)((unsigned)f2bf(v0[0]) | ((unsigned)f2bf(v0[1]) << 16));
  p[1] = (int)((unsigned)f2bf(v0[2]) | ((unsigned)f2bf(v0[3]) << 16));
  p[2] = (int)((unsigned)f2bf(v1[0]) | ((unsigned)f2bf(v1[1]) << 16));
  p[3] = (int)((unsigned)f2bf(v1[2]) | ((unsigned)f2bf(v1[3]) << 16));
  int s0 = slotmap[tok * 2], s1 = slotmap[tok * 2 + 1];
  *(int4v*)(x_g + (size_t)s0 * HDIM + h) = p;
  *(int4v*)(x_g + (size_t)s1 * HDIM + h) = p;
}

// ---- weight transpose-convert preps ----
// W_in fp32 [8][1024][8192] -> W_in_t bf16 [e][J(64)][128 rows][1024 k]
__global__ __launch_bounds__(256) void prep_win_kernel(
    const float* __restrict__ W_in, unsigned short* __restrict__ Wt) {
  int e = blockIdx.z, k0 = blockIdx.y * 64, n0 = blockIdx.x * 64;
  __shared__ unsigned short T[64 * 72];
  int tid = threadIdx.x;
#pragma unroll
  for (int i = 0; i < 4; i++) {
    int q = i * 256 + tid;
    int kr = q >> 4, nc = (q & 15) * 4;
    float4v v = *(const float4v*)(W_in + ((size_t)e * 1024 + k0 + kr) * 8192 + n0 + nc);
#pragma unroll
    for (int j = 0; j < 4; j++) T[(nc + j) * 72 + kr] = f2bf(v[j]);
  }
  __syncthreads();
  int J = (n0 & 4095) >> 6;
  int rwb = (n0 >= 4096) ? 64 : 0;
  unsigned short* ob = Wt + (((size_t)e * 64 + J) * 128 + rwb) * 1024;
#pragma unroll
  for (int i = 0; i < 4; i++) {
    int q = i * 256 + tid;
    int nr = q >> 4, kc = (q & 15) * 4;
    ushort4v u;
#pragma unroll
    for (int j = 0; j < 4; j++) u[j] = T[nr * 72 + kc + j];
    *(ushort4v*)(ob + (size_t)nr * 1024 + k0 + kc) = u;
  }
}

// W_out fp32 [8][4096][1024] -> W_out_t bf16 [e][n=1024][k=4096]
__global__ __launch_bounds__(256) void prep_wout_kernel(
    const float* __restrict__ W_out, unsigned short* __restrict__ Wt) {
  int e = blockIdx.z, k0 = blockIdx.y * 64, n0 = blockIdx.x * 64;
  __shared__ unsigned short T[64 * 72];
  int tid = threadIdx.x;
#pragma unroll
  for (int i = 0; i < 4; i++) {
    int q = i * 256 + tid;
    int kr = q >> 4, nc = (q & 15) * 4;
    float4v v = *(const float4v*)(W_out + ((size_t)e * 4096 + k0 + kr) * 1024 + n0 + nc);
#pragma unroll
    for (int j = 0; j < 4; j++) T[(nc + j) * 72 + kr] = f2bf(v[j]);
  }
  __syncthreads();
  unsigned short* ob = Wt + ((size_t)e * 1024 + n0) * 4096;
#pragma unroll
  for (int i = 0; i < 4; i++) {
    int q = i * 256 + tid;
    int nr = q >> 4, kc = (q & 15) * 4;
    ushort4v u;
#pragma unroll
    for (int j = 0; j < 4; j++) u[j] = T[nr * 72 + kc + j];
    *(ushort4v*)(ob + (size_t)nr * 4096 + k0 + kc) = u;
  }
}

// ---- GEMM1: m97-style, global_load_lds + XOR-swizzled frag reads ----
__global__ __launch_bounds__(256) void gemm1a_kernel(
    const unsigned short* __restrict__ x_g, const unsigned short* __restrict__ Wt,
    const float* __restrict__ b_in, unsigned short* __restrict__ a_buf,
    const int* __restrict__ meta) {
  int t = blockIdx.x;
  if (t >= meta[MC_NTILES]) return;
  int e = meta[MC_TILE_E + t];
  int m0 = meta[MC_TILE_M0 + t];
  int rows = meta[MC_TILE_RW + t];
  int J = blockIdx.y;
  const unsigned short* Wp = Wt + (((size_t)e * 64 + J) << 17);  // *128*1024

  __shared__ __align__(16) unsigned short As[128 * 64];
  __shared__ __align__(16) unsigned short Bs[128 * 64];

  int tid = threadIdx.x, l = tid & 63, w = tid >> 6, g = l >> 4, ln = l & 15;
  int lr = l >> 3;
  int uc = (l & 7) ^ lr;   // swizzled source 16B-unit

  const unsigned short* sA[4]; const unsigned short* sB[4];
  unsigned short* dA[4]; unsigned short* dB[4];
#pragma unroll
  for (int i = 0; i < 4; i++) {
    int c = w * 4 + i;
    int r = c * 8 + lr;
    int ra = r < rows ? r : rows - 1;
    sA[i] = x_g + (size_t)(m0 + ra) * HDIM + uc * 8;
    sB[i] = Wp + (size_t)r * 1024 + uc * 8;
    dA[i] = &As[c * 512 + l * 8];
    dB[i] = &Bs[c * 512 + l * 8];
  }

  f32x4 acc[2][8];
#pragma unroll
  for (int mf = 0; mf < 2; mf++)
#pragma unroll
    for (int nf = 0; nf < 8; nf++) acc[mf][nf] = (f32x4){0.f, 0.f, 0.f, 0.f};

  for (int kt = 0; kt < 16; kt++) {
#pragma unroll
    for (int i = 0; i < 4; i++) gload16(sA[i] + kt * 64, dA[i]);
#pragma unroll
    for (int i = 0; i < 4; i++) gload16(sB[i] + kt * 64, dB[i]);
    __syncthreads();
#pragma unroll
    for (int ks = 0; ks < 2; ks++) {
      int u0 = (((ks * 4 + g) ^ (ln & 7)) << 3);
      int r0 = w * 32 + ln;
      short8 a0 = *(const short8*)&As[r0 * 64 + u0];
      short8 a1 = *(const short8*)&As[(r0 + 16) * 64 + u0];
#pragma unroll
      for (int nf = 0; nf < 8; nf++) {
        short8 bv = *(const short8*)&Bs[(nf * 16 + ln) * 64 + u0];
        acc[0][nf] = mfma_bf16(a0, bv, acc[0][nf]);
        acc[1][nf] = mfma_bf16(a1, bv, acc[1][nf]);
      }
    }
    __syncthreads();
  }
#pragma unroll
  for (int mf = 0; mf < 2; mf++) {
#pragma unroll
    for (int nf = 0; nf < 4; nf++) {
      int jl = nf * 16 + ln;
      float b1 = b_in[(size_t)e * 8192 + J * 64 + jl];
      float b2 = b_in[(size_t)e * 8192 + 4096 + J * 64 + jl];
#pragma unroll
      for (int r = 0; r < 4; r++) {
        int m = w * 32 + mf * 16 + g * 4 + r;
        if (m < rows) {
          float h1 = acc[mf][nf][r] + b1;
          float h2 = acc[mf][nf + 4][r] + b2;
          a_buf[(size_t)(m0 + m) * IDIM + J * 64 + jl] = f2bf(h1 / (1.f + __expf(-h2)));
        }
      }
    }
  }
}

// ---- GEMM2: 128m x 64n tile, K=4096, same staging/swizzle ----
__global__ __launch_bounds__(256) void gemm2a_kernel(
    const unsigned short* __restrict__ a_buf, const unsigned short* __restrict__ Wt,
    const float* __restrict__ b_out, unsigned short* __restrict__ buf2,
    const int* __restrict__ meta) {
  int t = blockIdx.x;
  if (t >= meta[MC_NTILES]) return;
  int e = meta[MC_TILE_E + t];
  int m0 = meta[MC_TILE_M0 + t];
  int rows = meta[MC_TILE_RW + t];
  int n0 = blockIdx.y * 64;
  const unsigned short* Wp = Wt + ((size_t)e * 1024 + n0) * 4096;

  __shared__ __align__(16) unsigned short As[128 * 64];
  __shared__ __align__(16) unsigned short Bs[64 * 64];

  int tid = threadIdx.x, l = tid & 63, w = tid >> 6, g = l >> 4, ln = l & 15;
  int lr = l >> 3;
  int uc = (l & 7) ^ lr;

  const unsigned short* sA[4]; const unsigned short* sB[2];
  unsigned short* dA[4]; unsigned short* dB[2];
#pragma unroll
  for (int i = 0; i < 4; i++) {
    int c = w * 4 + i;
    int r = c * 8 + lr;
    int ra = r < rows ? r : rows - 1;
    sA[i] = a_buf + (size_t)(m0 + ra) * IDIM + uc * 8;
    dA[i] = &As[c * 512 + l * 8];
  }
#pragma unroll
  for (int i = 0; i < 2; i++) {
    int c = w * 2 + i;
    int r = c * 8 + lr;
    sB[i] = Wp + (size_t)r * 4096 + uc * 8;
    dB[i] = &Bs[c * 512 + l * 8];
  }

  f32x4 acc[2][4];
#pragma unroll
  for (int mf = 0; mf < 2; mf++)
#pragma unroll
    for (int nf = 0; nf < 4; nf++) acc[mf][nf] = (f32x4){0.f, 0.f, 0.f, 0.f};

  for (int kt = 0; kt < 64; kt++) {
#pragma unroll
    for (int i = 0; i < 4; i++) gload16(sA[i] + kt * 64, dA[i]);
#pragma unroll
    for (int i = 0; i < 2; i++) gload16(sB[i] + kt * 64, dB[i]);
    __syncthreads();
#pragma unroll
    for (int ks = 0; ks < 2; ks++) {
      int u0 = (((ks * 4 + g) ^ (ln & 7)) << 3);
      int r0 = w * 32 + ln;
      short8 a0 = *(const short8*)&As[r0 * 64 + u0];
      short8 a1 = *(const short8*)&As[(r0 + 16) * 64 + u0];
#pragma unroll
      for (int nf = 0; nf < 4; nf++) {
        short8 bv = *(const short8*)&Bs[(nf * 16 + ln) * 64 + u0];
        acc[0][nf] = mfma_bf16(a0, bv, acc[0][nf]);
        acc[1][nf] = mfma_bf16(a1, bv, acc[1][nf]);
      }
    }
    __syncthreads();
  }
#pragma unroll
  for (int mf = 0; mf < 2; mf++) {
#pragma unroll
    for (int nf = 0; nf < 4; nf++) {
      int nl = nf * 16 + ln;
      float bo = b_out[(size_t)e * 1024 + n0 + nl];
#pragma unroll
      for (int r = 0; r < 4; r++) {
        int m = w * 32 + mf * 16 + g * 4 + r;
        if (m < rows) {
          buf2[(size_t)(m0 + m) * HDIM + n0 + nl] = f2bf(acc[mf][nf][r] + bo);
        }
      }
    }
  }
}

// out[b] = w0 * buf2[slot0] + w1 * buf2[slot1]  (fp32, deterministic order)
__global__ __launch_bounds__(256) void combine_kernel(
    const unsigned short* __restrict__ buf2, const int* __restrict__ slotmap,
    const float* __restrict__ wmap, float* __restrict__ out) {
  int i = blockIdx.x * 256 + threadIdx.x;
  int base = i * 4;
  int b = base >> 10, h = base & 1023;
  int s0 = slotmap[b * 2], s1 = slotmap[b * 2 + 1];
  float w0 = wmap[b * 2], w1 = wmap[b * 2 + 1];
  ushort4v c0 = *(const ushort4v*)(buf2 + (size_t)s0 * HDIM + h);
  ushort4v c1 = *(const ushort4v*)(buf2 + (size_t)s1 * HDIM + h);
  float4v o;
#pragma unroll
  for (int j = 0; j < 4; j++) o[j] = w0 * bf2f(c0[j]) + w1 * bf2f(c1[j]);
  *(float4v*)(out + base) = o;
}

extern "C" void kernel_launch(void* const* d_in, const int* in_sizes, int n_in,
                              void* d_out, int out_size, void* d_ws, size_t ws_size,
                              hipStream_t stream) {
  const float* x     = (const float*)d_in[0];
  const float* noise = (const float*)d_in[1];
  const float* Wr    = (const float*)d_in[2];
  const float* br    = (const float*)d_in[3];
  const float* W_in  = (const float*)d_in[4];
  const float* b_in  = (const float*)d_in[5];
  const float* W_out = (const float*)d_in[6];
  const float* b_out = (const float*)d_in[7];
  float* out = (float*)d_out;
  char* ws = (char*)d_ws;

  // Path A layout (~208 MB, confirmed available in round 2).
  // Aliasing via stream order: W_out_t overwrites W_in_t after gemm1;
  // buf2 overwrites x_g after gemm1.
  unsigned short* W_in_t  = (unsigned short*)ws;                      // 128 MB
  unsigned short* W_out_t = W_in_t;                                   // 64 MB (after gemm1)
  unsigned short* x_g     = (unsigned short*)(ws + 134217728);        // 16 MB
  unsigned short* buf2    = x_g;                                      // (after gemm1)
  unsigned short* a_buf   = (unsigned short*)(ws + 150994944);        // 64 MB
  int* meta    = (int*)(ws + 218103808);
  int* idxmap  = meta + META_INTS;
  int* slotmap = idxmap + NSLOT;
  float* wmap  = (float*)(slotmap + NSLOT);

  hipLaunchKernelGGL(router_kernel, dim3(B_TOK / 4), dim3(256), 0, stream,
                     x, noise, Wr, br, idxmap, wmap);
  hipLaunchKernelGGL(rank_kernel, dim3(1), dim3(1024), 0, stream,
                     idxmap, slotmap, meta);
  hipLaunchKernelGGL(place_kernel, dim3(B_TOK / 2), dim3(256), 0, stream,
                     x, slotmap, x_g);
  hipLaunchKernelGGL(prep_win_kernel, dim3(128, 16, 8), dim3(256), 0, stream,
                     W_in, W_in_t);
  hipLaunchKernelGGL(gemm1a_kernel, dim3(MAX_TILES, 64), dim3(256), 0, stream,
                     x_g, W_in_t, b_in, a_buf, meta);
  hipLaunchKernelGGL(prep_wout_kernel, dim3(16, 64, 8), dim3(256), 0, stream,
                     W_out, W_out_t);
  hipLaunchKernelGGL(gemm2a_kernel, dim3(MAX_TILES, 16), dim3(256), 0, stream,
                     a_buf, W_out_t, b_out, buf2, meta);
  hipLaunchKernelGGL(combine_kernel, dim3((B_TOK * HDIM / 4) / 256), dim3(256), 0, stream,
                     buf2, slotmap, wmap, out);
}